// Round 10
// baseline (577.796 us; speedup 1.0000x reference)
//
#include <hip/hip_runtime.h>

#define NN 100000
#define NE 600000
#define DIM 128
#define NG 256
#define NB_SCAN 391  // ceil(NN/256)
#define FILL_NB 2344 // ceil(NE/256)
#define PREP_NB 128
#define EMB_NB 25000 // NN/4

typedef __attribute__((ext_vector_type(8))) short short8_t;
typedef __attribute__((ext_vector_type(4))) float f32x4;

__device__ __forceinline__ ushort f2bf(float f) {
  unsigned u = __float_as_uint(f);
  unsigned r = (u + 0x7fffu + ((u >> 16) & 1u)) >> 16;
  return (ushort)r;
}
__device__ __forceinline__ float bf2f(ushort h) {
  return __uint_as_float(((unsigned)h) << 16);
}

// ---------------- CSR: degree ----------------
__global__ __launch_bounds__(256) void deg_int_kernel(const int* __restrict__ dst,
                                                      int* __restrict__ degi) {
  int e = blockIdx.x * 256 + threadIdx.x;
  if (e < NE) atomicAdd(degi + dst[e], 1);
}

// ---------------- CSR: per-block scan ----------------
__global__ __launch_bounds__(256) void scan1_kernel(const int* __restrict__ degi,
                                                    int* __restrict__ excl,
                                                    int* __restrict__ bsum) {
  __shared__ int tmp[256];
  int t = threadIdx.x;
  int i = blockIdx.x * 256 + t;
  int v = (i < NN) ? degi[i] : 0;
  int val = v;
  tmp[t] = val;
  __syncthreads();
  for (int off = 1; off < 256; off <<= 1) {
    int add = (t >= off) ? tmp[t - off] : 0;
    __syncthreads();
    val += add;
    tmp[t] = val;
    __syncthreads();
  }
  if (i < NN) excl[i] = val - v;
  if (t == 255) bsum[blockIdx.x] = val;
}

// ---------------- CSR: block-offset + row_off + cursor (scan2+scan3 merged) ----
__global__ __launch_bounds__(256) void scan23_kernel(const int* __restrict__ excl,
                                                     const int* __restrict__ bsum,
                                                     int* __restrict__ row_off,
                                                     int* __restrict__ cursor) {
  __shared__ int sh[256];
  int blk = blockIdx.x;
  int t = threadIdx.x;
  int partial = 0;
  for (int j = t; j < blk; j += 256) partial += bsum[j];
  sh[t] = partial;
  __syncthreads();
  for (int off = 128; off; off >>= 1) {
    if (t < off) sh[t] += sh[t + off];
    __syncthreads();
  }
  int base = sh[0];
  int i = blk * 256 + t;
  if (i < NN) {
    int r = excl[i] + base;
    row_off[i] = r;
    cursor[i] = r;
  }
  if (i == NN) row_off[NN] = NE;
}

// ---------------- device bodies for the mega kernel ----------------
__device__ __forceinline__ void fill_body(int bid, int t, const int* __restrict__ src,
                                          const int* __restrict__ dst,
                                          int* __restrict__ cursor,
                                          int* __restrict__ csr_src) {
  int e = bid * 256 + t;
  if (e < NE) {
    int d = dst[e];
    int slot = atomicAdd(cursor + d, 1);
    csr_src[slot] = src[e];
  }
}

// wp layout: [p][hl][j][ht][lane][8]; k = p*64 + j*32 + lq*4 + (e&3) + 16*(e>>2);
// k<128 -> wl (agg term, p=0,1), k>=128 -> wr (self term, p=2,3).
__device__ __forceinline__ void prep_body(int idx, const float* __restrict__ wl,
                                          const float* __restrict__ wr,
                                          ushort* __restrict__ wp) {
  int e = idx & 7;
  int lane = (idx >> 3) & 63;
  int ht = (idx >> 9) & 7;
  int j = (idx >> 12) & 1;
  int p = (idx >> 13) & 3;
  int h = ht * 16 + (lane & 15);
  int lq = lane >> 4;
  int k = p * 64 + j * 32 + lq * 4 + (e & 3) + 16 * (e >> 2);
  float v = (k < 128) ? wl[h * 128 + k] : wr[h * 128 + (k - 128)];
  ushort hi = f2bf(v);
  ushort lo = f2bf(v - bf2f(hi));
  wp[(((p * 2 + 0) * 2 + j) * 8 + ht) * 512 + lane * 8 + e] = hi;
  wp[(((p * 2 + 1) * 2 + j) * 8 + ht) * 512 + lane * 8 + e] = lo;
}

__device__ __forceinline__ void embed_body(int bid, int t, const int* __restrict__ x_idx,
                                           const float* __restrict__ emb,
                                           const float* __restrict__ g,
                                           const float* __restrict__ b,
                                           float* __restrict__ out) {
  int wave = t >> 6;
  int lane = t & 63;
  int n = bid * 4 + wave;
  if (n >= NN) return;
  int idx = x_idx[n];
  float2 v = ((const float2*)(emb + (size_t)idx * DIM))[lane];
  float s = v.x + v.y;
  float sq = v.x * v.x + v.y * v.y;
  for (int off = 32; off; off >>= 1) {
    s += __shfl_xor(s, off);
    sq += __shfl_xor(sq, off);
  }
  float m = s * (1.0f / 128.0f);
  float var = sq * (1.0f / 128.0f) - m * m;
  float r = rsqrtf(var + 1e-5f);
  float2 gg = ((const float2*)g)[lane];
  float2 bb = ((const float2*)b)[lane];
  float2 o;
  o.x = (v.x - m) * r * gg.x + bb.x;
  o.y = (v.y - m) * r * gg.y + bb.y;
  ((float2*)(out + (size_t)n * DIM))[lane] = o;
}

// ---------------- mega kernel: fill | prep_w x2 | embed_ln ----------------
__global__ __launch_bounds__(256) void mega_kernel(
    const int* __restrict__ src, const int* __restrict__ dst,
    int* __restrict__ cursor, int* __restrict__ csr_src,
    const float* __restrict__ w0l, const float* __restrict__ w0r, ushort* __restrict__ wp0,
    const float* __restrict__ w1l, const float* __restrict__ w1r, ushort* __restrict__ wp1,
    const int* __restrict__ x_idx, const float* __restrict__ emb,
    const float* __restrict__ ln0g, const float* __restrict__ ln0b,
    float* __restrict__ x) {
  int bid = blockIdx.x;
  int t = threadIdx.x;
  if (bid < FILL_NB) {
    fill_body(bid, t, src, dst, cursor, csr_src);
  } else if (bid < FILL_NB + PREP_NB) {
    prep_body((bid - FILL_NB) * 256 + t, w0l, w0r, wp0);
  } else if (bid < FILL_NB + 2 * PREP_NB) {
    prep_body((bid - FILL_NB - PREP_NB) * 256 + t, w1l, w1r, wp1);
  } else {
    embed_body(bid - FILL_NB - 2 * PREP_NB, t, x_idx, emb, ln0g, ln0b, x);
  }
}

// ---------------- fused SAGE layer: gather-mean + split-bf16 MFMA conv --------
// out = relu([mean_nbr(xin)|xin] @ Wcat^T + bl) (+ optional fused LN), fp32.
// Block = 128 nodes, 4 waves each 32 nodes x 128 h.
// 1) gather: 16 rounds x 8 nodes, mean in regs, split-bf16 frags -> LDS (64 KB)
// 2) one barrier
// 3) 8 k-steps: A-agg from LDS, A-self direct from global x (+on-the-fly split),
//    B direct from pre-permuted wp (L2). No other barriers.
__global__ __launch_bounds__(256, 2) void sage_kernel(
    const float* __restrict__ xin, const int* __restrict__ row_off,
    const int* __restrict__ csr_src, const ushort* __restrict__ wp,
    const float* __restrict__ bl, const float* __restrict__ lng,
    const float* __restrict__ lnb, float* __restrict__ out, int do_ln) {
  __shared__ ushort Aagg[8 * 4 * 2 * 64 * 8];  // [g][jb][hl][lane][e] = 64 KB
  const int t = threadIdx.x;
  const int lane = t & 63;
  const int wv = t >> 6;
  const int l15 = lane & 15;
  const int lq = lane >> 4;
  const int nbase = blockIdx.x * 128;

  // ======== gather phase ========
  {
    const int q = t & 31;
    const int nr = t >> 5;  // 0..7
    const int jb = q >> 3, lqw = q & 3, ebase = q & 4;
#pragma unroll 1
    for (int r = 0; r < 16; ++r) {
      int nl = r * 8 + nr;  // local node 0..127
      int node = nbase + nl;
      float4 a4 = make_float4(0.f, 0.f, 0.f, 0.f);
      int beg = 0, end = 0;
      if (node < NN) { beg = row_off[node]; end = row_off[node + 1]; }
      int e = beg;
      int s = (e < end) ? csr_src[e] : 0;
      while (e < end) {
        int snx = (e + 1 < end) ? csr_src[e + 1] : 0;
        float4 v = ((const float4*)(xin + (size_t)s * DIM))[q];
        a4.x += v.x; a4.y += v.y; a4.z += v.z; a4.w += v.w;
        s = snx;
        ++e;
      }
      float sc = 1.0f / fmaxf((float)(end - beg), 1.0f);
      a4.x *= sc; a4.y *= sc; a4.z *= sc; a4.w *= sc;
      ushort4 hi, lo;
      hi.x = f2bf(a4.x); lo.x = f2bf(a4.x - bf2f(hi.x));
      hi.y = f2bf(a4.y); lo.y = f2bf(a4.y - bf2f(hi.y));
      hi.z = f2bf(a4.z); lo.z = f2bf(a4.z - bf2f(hi.z));
      hi.w = f2bf(a4.w); lo.w = f2bf(a4.w - bf2f(hi.w));
      int g = nl >> 4, l15n = nl & 15;
      int bh = (((g * 4 + jb) * 2 + 0) * 64 + lqw * 16 + l15n) * 8;
      *(ushort4*)(Aagg + bh + ebase) = hi;
      *(ushort4*)(Aagg + bh + 512 + ebase) = lo;  // hl=1 block
    }
  }
  __syncthreads();

  // ======== MFMA phase ========
  f32x4 acc[2][8];
#pragma unroll
  for (int a = 0; a < 2; ++a)
#pragma unroll
    for (int b = 0; b < 8; ++b) acc[a][b] = (f32x4){0.f, 0.f, 0.f, 0.f};

  // agg half: jb = 0..3 (Wcat k 0..127 -> wp pk = jb>>1, j = jb&1)
#pragma unroll
  for (int jb = 0; jb < 4; ++jb) {
    const int pk = jb >> 1, j = jb & 1;
    short8_t ahi[2], alo[2];
#pragma unroll
    for (int nt = 0; nt < 2; ++nt) {
      int gl = wv * 2 + nt;
      int ba = (((gl * 4 + jb) * 2 + 0) * 64 + lane) * 8;
      ahi[nt] = *(const short8_t*)(Aagg + ba);
      alo[nt] = *(const short8_t*)(Aagg + ba + 512);
    }
#pragma unroll
    for (int ht = 0; ht < 8; ++ht) {
      short8_t bhi = *(const short8_t*)(wp + (((pk * 2 + 0) * 2 + j) * 8 + ht) * 512 + lane * 8);
      short8_t blo = *(const short8_t*)(wp + (((pk * 2 + 1) * 2 + j) * 8 + ht) * 512 + lane * 8);
      acc[0][ht] = __builtin_amdgcn_mfma_f32_16x16x32_bf16(ahi[0], bhi, acc[0][ht], 0, 0, 0);
      acc[1][ht] = __builtin_amdgcn_mfma_f32_16x16x32_bf16(ahi[1], bhi, acc[1][ht], 0, 0, 0);
      acc[0][ht] = __builtin_amdgcn_mfma_f32_16x16x32_bf16(alo[0], bhi, acc[0][ht], 0, 0, 0);
      acc[1][ht] = __builtin_amdgcn_mfma_f32_16x16x32_bf16(alo[1], bhi, acc[1][ht], 0, 0, 0);
      acc[0][ht] = __builtin_amdgcn_mfma_f32_16x16x32_bf16(ahi[0], blo, acc[0][ht], 0, 0, 0);
      acc[1][ht] = __builtin_amdgcn_mfma_f32_16x16x32_bf16(ahi[1], blo, acc[1][ht], 0, 0, 0);
    }
  }

  // self half: pks = 0..3 (Wcat k 128..255 -> wp pk = 2+(pks>>1), j = pks&1)
#pragma unroll
  for (int pks = 0; pks < 4; ++pks) {
    const int pk = 2 + (pks >> 1), j = pks & 1;
    short8_t ahi[2], alo[2];
#pragma unroll
    for (int nt = 0; nt < 2; ++nt) {
      int node = nbase + wv * 32 + nt * 16 + l15;
      float4 fa = make_float4(0.f, 0.f, 0.f, 0.f);
      float4 fb = make_float4(0.f, 0.f, 0.f, 0.f);
      if (node < NN) {
        const float* rp = xin + (size_t)node * DIM + pks * 32 + lq * 4;
        fa = *(const float4*)rp;
        fb = *(const float4*)(rp + 16);
      }
      float f[8] = {fa.x, fa.y, fa.z, fa.w, fb.x, fb.y, fb.z, fb.w};
      short8_t h, l;
#pragma unroll
      for (int e = 0; e < 8; ++e) {
        ushort hh = f2bf(f[e]);
        h[e] = (short)hh;
        l[e] = (short)f2bf(f[e] - bf2f(hh));
      }
      ahi[nt] = h;
      alo[nt] = l;
    }
#pragma unroll
    for (int ht = 0; ht < 8; ++ht) {
      short8_t bhi = *(const short8_t*)(wp + (((pk * 2 + 0) * 2 + j) * 8 + ht) * 512 + lane * 8);
      short8_t blo = *(const short8_t*)(wp + (((pk * 2 + 1) * 2 + j) * 8 + ht) * 512 + lane * 8);
      acc[0][ht] = __builtin_amdgcn_mfma_f32_16x16x32_bf16(ahi[0], bhi, acc[0][ht], 0, 0, 0);
      acc[1][ht] = __builtin_amdgcn_mfma_f32_16x16x32_bf16(ahi[1], bhi, acc[1][ht], 0, 0, 0);
      acc[0][ht] = __builtin_amdgcn_mfma_f32_16x16x32_bf16(alo[0], bhi, acc[0][ht], 0, 0, 0);
      acc[1][ht] = __builtin_amdgcn_mfma_f32_16x16x32_bf16(alo[1], bhi, acc[1][ht], 0, 0, 0);
      acc[0][ht] = __builtin_amdgcn_mfma_f32_16x16x32_bf16(ahi[0], blo, acc[0][ht], 0, 0, 0);
      acc[1][ht] = __builtin_amdgcn_mfma_f32_16x16x32_bf16(ahi[1], blo, acc[1][ht], 0, 0, 0);
    }
  }

  // ======== epilogue: bias + relu (+ fused LN), fp32 row-major store ========
#pragma unroll
  for (int ht = 0; ht < 8; ++ht) {
    float bv = bl[ht * 16 + l15];
#pragma unroll
    for (int nt = 0; nt < 2; ++nt)
#pragma unroll
      for (int r = 0; r < 4; ++r) acc[nt][ht][r] = fmaxf(acc[nt][ht][r] + bv, 0.f);
  }
  if (do_ln) {
    float gg[8], bb[8];
#pragma unroll
    for (int ht = 0; ht < 8; ++ht) {
      gg[ht] = lng[ht * 16 + l15];
      bb[ht] = lnb[ht * 16 + l15];
    }
#pragma unroll
    for (int nt = 0; nt < 2; ++nt) {
#pragma unroll
      for (int r = 0; r < 4; ++r) {
        float s = 0.f, sq = 0.f;
#pragma unroll
        for (int ht = 0; ht < 8; ++ht) {
          float v = acc[nt][ht][r];
          s += v;
          sq += v * v;
        }
#pragma unroll
        for (int msk = 1; msk < 16; msk <<= 1) {
          s += __shfl_xor(s, msk);
          sq += __shfl_xor(sq, msk);
        }
        float m = s * (1.0f / 128.0f);
        float var = sq * (1.0f / 128.0f) - m * m;
        float rstd = rsqrtf(var + 1e-5f);
        int node = nbase + wv * 32 + nt * 16 + lq * 4 + r;
        if (node < NN) {
#pragma unroll
          for (int ht = 0; ht < 8; ++ht)
            out[(size_t)node * DIM + ht * 16 + l15] =
                (acc[nt][ht][r] - m) * rstd * gg[ht] + bb[ht];
        }
      }
    }
  } else {
#pragma unroll
    for (int nt = 0; nt < 2; ++nt) {
#pragma unroll
      for (int r = 0; r < 4; ++r) {
        int node = nbase + wv * 32 + nt * 16 + lq * 4 + r;
        if (node < NN) {
#pragma unroll
          for (int ht = 0; ht < 8; ++ht)
            out[(size_t)node * DIM + ht * 16 + l15] = acc[nt][ht][r];
        }
      }
    }
  }
}

// ---------------- mean pool over sorted batch ----------------
#define PCHUNK 128
__global__ __launch_bounds__(128) void pool_kernel(const float* __restrict__ x,
                                                   const int* __restrict__ batch,
                                                   float* __restrict__ pool,
                                                   float* __restrict__ cnt) {
  int f = threadIdx.x;
  int n0 = blockIdx.x * PCHUNK;
  float acc = 0.f;
  int cur = batch[n0];
  int runlen = 0;
  for (int i = 0; i < PCHUNK; ++i) {
    int n = n0 + i;
    if (n >= NN) break;
    int bg = batch[n];
    if (bg != cur) {
      atomicAdd(&pool[cur * DIM + f], acc);
      if (f == 0) atomicAdd(&cnt[cur], (float)runlen);
      acc = 0.f;
      runlen = 0;
      cur = bg;
    }
    acc += x[(size_t)n * DIM + f];
    runlen++;
  }
  if (runlen > 0) {
    atomicAdd(&pool[cur * DIM + f], acc);
    if (f == 0) atomicAdd(&cnt[cur], (float)runlen);
  }
}

// ---------------- MLP head ----------------
__global__ __launch_bounds__(128) void head_kernel(
    const float* __restrict__ pool, const float* __restrict__ cnt,
    const float* __restrict__ w1, const float* __restrict__ b1,
    const float* __restrict__ w2, const float* __restrict__ b2,
    float* __restrict__ out) {
  __shared__ float gsh[128];
  __shared__ float h[64];
  int g = blockIdx.x;
  int t = threadIdx.x;
  float ic = 1.0f / fmaxf(cnt[g], 1.0f);
  gsh[t] = pool[g * DIM + t] * ic;
  __syncthreads();
  if (t < 64) {
    float a = b1[t];
#pragma unroll 8
    for (int k = 0; k < 128; ++k) a += gsh[k] * w1[t * 128 + k];
    h[t] = fmaxf(a, 0.f);
  }
  __syncthreads();
  if (t < 2) {
    float a = b2[t];
#pragma unroll
    for (int k = 0; k < 64; ++k) a += h[k] * w2[t * 64 + k];
    out[g * 2 + t] = a;
  }
}

extern "C" void kernel_launch(void* const* d_in, const int* in_sizes, int n_in,
                              void* d_out, int out_size, void* d_ws, size_t ws_size,
                              hipStream_t stream) {
  const int* x_idx = (const int*)d_in[0];
  const int* eidx = (const int*)d_in[1];
  const int* batch = (const int*)d_in[2];
  const float* emb = (const float*)d_in[3];
  const float* ln0g = (const float*)d_in[4];
  const float* ln0b = (const float*)d_in[5];
  const float* w0l = (const float*)d_in[6];
  const float* b0l = (const float*)d_in[7];
  const float* w0r = (const float*)d_in[8];
  const float* ln1g = (const float*)d_in[9];
  const float* ln1b = (const float*)d_in[10];
  const float* w1l = (const float*)d_in[11];
  const float* b1l = (const float*)d_in[12];
  const float* w1r = (const float*)d_in[13];
  const float* mw1 = (const float*)d_in[14];
  const float* mb1 = (const float*)d_in[15];
  const float* mw2 = (const float*)d_in[16];
  const float* mb2 = (const float*)d_in[17];
  float* out = (float*)d_out;

  float* ws = (float*)d_ws;
  float* x = ws;                                   // NN*DIM fp32
  float* y = x + (size_t)NN * DIM;                 // NN*DIM fp32 (ping-pong)
  float* pool = y + (size_t)NN * DIM;              // NG*DIM
  float* cnt = pool + (size_t)NG * DIM;            // NG
  int* degi = (int*)(cnt + NG);                    // NN   (contig w/ pool,cnt for memset)
  int* excl = degi + NN;                           // NN
  int* row_off = excl + NN;                        // NN+1
  int* cursor = row_off + NN + 1;                  // NN
  int* bsum = cursor + NN;                         // 512
  int* csr_src = bsum + 512;                       // NE
  ushort* wp0 = (ushort*)(csr_src + NE);           // 65536 ushort each
  ushort* wp1 = wp0 + 65536;

  const int* src = eidx;
  const int* dst = eidx + NE;

  // one memset: pool + cnt + degi are contiguous
  hipMemsetAsync(pool, 0, ((size_t)NG * DIM + NG + NN) * sizeof(float), stream);

  deg_int_kernel<<<FILL_NB, 256, 0, stream>>>(dst, degi);
  scan1_kernel<<<NB_SCAN, 256, 0, stream>>>(degi, excl, bsum);
  scan23_kernel<<<NB_SCAN, 256, 0, stream>>>(excl, bsum, row_off, cursor);
  mega_kernel<<<FILL_NB + 2 * PREP_NB + EMB_NB, 256, 0, stream>>>(
      src, dst, cursor, csr_src, w0l, w0r, wp0, w1l, w1r, wp1, x_idx, emb, ln0g, ln0b, x);

  // layer 0: x -> y (LN1 fused); layer 1: y -> x
  sage_kernel<<<(NN + 127) / 128, 256, 0, stream>>>(x, row_off, csr_src, wp0, b0l,
                                                    ln1g, ln1b, y, 1);
  sage_kernel<<<(NN + 127) / 128, 256, 0, stream>>>(y, row_off, csr_src, wp1, b1l,
                                                    (const float*)0, (const float*)0, x, 0);

  pool_kernel<<<(NN + PCHUNK - 1) / PCHUNK, 128, 0, stream>>>(x, batch, pool, cnt);
  head_kernel<<<NG, 128, 0, stream>>>(pool, cnt, mw1, mb1, mw2, mb2, out);
}

// Round 12
// 547.814 us; speedup vs baseline: 1.0547x; 1.0547x over previous
//
#include <hip/hip_runtime.h>

#define NN 100000
#define NE 600000
#define DIM 128
#define NG 256
#define NGRP 6250   // NN/16
#define NB_SCAN 391  // ceil(NN/256)
#define FILL_NB 2344 // ceil(NE/256)
#define PREP_NB 128
#define EMB_NB 25000 // NN/4

typedef __attribute__((ext_vector_type(8))) short short8_t;
typedef __attribute__((ext_vector_type(4))) float f32x4;

__device__ __forceinline__ ushort f2bf(float f) {
  unsigned u = __float_as_uint(f);
  unsigned r = (u + 0x7fffu + ((u >> 16) & 1u)) >> 16;
  return (ushort)r;
}
__device__ __forceinline__ float bf2f(ushort h) {
  return __uint_as_float(((unsigned)h) << 16);
}

// ---------------- CSR: degree ----------------
__global__ __launch_bounds__(256) void deg_int_kernel(const int* __restrict__ dst,
                                                      int* __restrict__ degi) {
  int e = blockIdx.x * 256 + threadIdx.x;
  if (e < NE) atomicAdd(degi + dst[e], 1);
}

// ---------------- CSR: per-block scan ----------------
__global__ __launch_bounds__(256) void scan1_kernel(const int* __restrict__ degi,
                                                    int* __restrict__ excl,
                                                    int* __restrict__ bsum) {
  __shared__ int tmp[256];
  int t = threadIdx.x;
  int i = blockIdx.x * 256 + t;
  int v = (i < NN) ? degi[i] : 0;
  int val = v;
  tmp[t] = val;
  __syncthreads();
  for (int off = 1; off < 256; off <<= 1) {
    int add = (t >= off) ? tmp[t - off] : 0;
    __syncthreads();
    val += add;
    tmp[t] = val;
    __syncthreads();
  }
  if (i < NN) excl[i] = val - v;
  if (t == 255) bsum[blockIdx.x] = val;
}

// ---------------- CSR: block-offset + row_off + cursor ----------------
__global__ __launch_bounds__(256) void scan23_kernel(const int* __restrict__ excl,
                                                     const int* __restrict__ bsum,
                                                     int* __restrict__ row_off,
                                                     int* __restrict__ cursor) {
  __shared__ int sh[256];
  int blk = blockIdx.x;
  int t = threadIdx.x;
  int partial = 0;
  for (int j = t; j < blk; j += 256) partial += bsum[j];
  sh[t] = partial;
  __syncthreads();
  for (int off = 128; off; off >>= 1) {
    if (t < off) sh[t] += sh[t + off];
    __syncthreads();
  }
  int base = sh[0];
  int i = blk * 256 + t;
  if (i < NN) {
    int r = excl[i] + base;
    row_off[i] = r;
    cursor[i] = r;
  }
  if (i == NN) row_off[NN] = NE;
}

// ---------------- device bodies for the mega kernel ----------------
__device__ __forceinline__ void fill_body(int bid, int t, const int* __restrict__ src,
                                          const int* __restrict__ dst,
                                          int* __restrict__ cursor,
                                          int* __restrict__ csr_src) {
  int e = bid * 256 + t;
  if (e < NE) {
    int d = dst[e];
    int slot = atomicAdd(cursor + d, 1);
    csr_src[slot] = src[e];
  }
}

// wp layout: [p][hl][j][ht][lane][8]; k = p*64 + j*32 + lq*4 + (e&3) + 16*(e>>2);
// k<128 -> wl (agg term, p=0,1), k>=128 -> wr (self term, p=2,3).
__device__ __forceinline__ void prep_body(int idx, const float* __restrict__ wl,
                                          const float* __restrict__ wr,
                                          ushort* __restrict__ wp) {
  int e = idx & 7;
  int lane = (idx >> 3) & 63;
  int ht = (idx >> 9) & 7;
  int j = (idx >> 12) & 1;
  int p = (idx >> 13) & 3;
  int h = ht * 16 + (lane & 15);
  int lq = lane >> 4;
  int k = p * 64 + j * 32 + lq * 4 + (e & 3) + 16 * (e >> 2);
  float v = (k < 128) ? wl[h * 128 + k] : wr[h * 128 + (k - 128)];
  ushort hi = f2bf(v);
  ushort lo = f2bf(v - bf2f(hi));
  wp[(((p * 2 + 0) * 2 + j) * 8 + ht) * 512 + lane * 8 + e] = hi;
  wp[(((p * 2 + 1) * 2 + j) * 8 + ht) * 512 + lane * 8 + e] = lo;
}

__device__ __forceinline__ void embed_body(int bid, int t, const int* __restrict__ x_idx,
                                           const float* __restrict__ emb,
                                           const float* __restrict__ g,
                                           const float* __restrict__ b,
                                           float* __restrict__ out) {
  int wave = t >> 6;
  int lane = t & 63;
  int n = bid * 4 + wave;
  if (n >= NN) return;
  int idx = x_idx[n];
  float2 v = ((const float2*)(emb + (size_t)idx * DIM))[lane];
  float s = v.x + v.y;
  float sq = v.x * v.x + v.y * v.y;
  for (int off = 32; off; off >>= 1) {
    s += __shfl_xor(s, off);
    sq += __shfl_xor(sq, off);
  }
  float m = s * (1.0f / 128.0f);
  float var = sq * (1.0f / 128.0f) - m * m;
  float r = rsqrtf(var + 1e-5f);
  float2 gg = ((const float2*)g)[lane];
  float2 bb = ((const float2*)b)[lane];
  float2 o;
  o.x = (v.x - m) * r * gg.x + bb.x;
  o.y = (v.y - m) * r * gg.y + bb.y;
  ((float2*)(out + (size_t)n * DIM))[lane] = o;
}

// ---------------- mega kernel: fill | prep_w x2 | embed_ln ----------------
__global__ __launch_bounds__(256) void mega_kernel(
    const int* __restrict__ src, const int* __restrict__ dst,
    int* __restrict__ cursor, int* __restrict__ csr_src,
    const float* __restrict__ w0l, const float* __restrict__ w0r, ushort* __restrict__ wp0,
    const float* __restrict__ w1l, const float* __restrict__ w1r, ushort* __restrict__ wp1,
    const int* __restrict__ x_idx, const float* __restrict__ emb,
    const float* __restrict__ ln0g, const float* __restrict__ ln0b,
    float* __restrict__ x) {
  int bid = blockIdx.x;
  int t = threadIdx.x;
  if (bid < FILL_NB) {
    fill_body(bid, t, src, dst, cursor, csr_src);
  } else if (bid < FILL_NB + PREP_NB) {
    prep_body((bid - FILL_NB) * 256 + t, w0l, w0r, wp0);
  } else if (bid < FILL_NB + 2 * PREP_NB) {
    prep_body((bid - FILL_NB - PREP_NB) * 256 + t, w1l, w1r, wp1);
  } else {
    embed_body(bid - FILL_NB - 2 * PREP_NB, t, x_idx, emb, ln0g, ln0b, x);
  }
}

// ---------------- gather mean -> fragment-layout agg ----------------
// af layout (ushort): [g16][jb(4)][lane(64)][hl(2)][e(8)], lane=(lq*16+l15),
// node n = g16*16+l15, k = jb*32 + lq*4 + (e&3) + 16*(e>>2).
__global__ __launch_bounds__(256) void gather_mean_kernel(
    const int* __restrict__ row_off, const int* __restrict__ csr_src,
    const float* __restrict__ x, ushort* __restrict__ af) {
  int t = threadIdx.x;
  int q = t & 31;
  int node = blockIdx.x * 8 + (t >> 5);
  if (node >= NN) return;
  int beg = row_off[node], end = row_off[node + 1];
  float4 acc = make_float4(0.f, 0.f, 0.f, 0.f);
  for (int e = beg; e < end; ++e) {
    int s = csr_src[e];
    float4 v = ((const float4*)(x + (size_t)s * DIM))[q];
    acc.x += v.x; acc.y += v.y; acc.z += v.z; acc.w += v.w;
  }
  float sc = 1.0f / fmaxf((float)(end - beg), 1.0f);
  acc.x *= sc; acc.y *= sc; acc.z *= sc; acc.w *= sc;
  ushort4 hi, lo;
  hi.x = f2bf(acc.x); lo.x = f2bf(acc.x - bf2f(hi.x));
  hi.y = f2bf(acc.y); lo.y = f2bf(acc.y - bf2f(hi.y));
  hi.z = f2bf(acc.z); lo.z = f2bf(acc.z - bf2f(hi.z));
  hi.w = f2bf(acc.w); lo.w = f2bf(acc.w - bf2f(hi.w));
  int g = node >> 4, l15n = node & 15;
  int jb = q >> 3, lqw = q & 3, ebase = q & 4;
  size_t base = (((size_t)g * 4 + jb) * 64 + lqw * 16 + l15n) * 16;
  *(ushort4*)(af + base + ebase) = hi;
  *(ushort4*)(af + base + 8 + ebase) = lo;
}

// ---------------- SAGE conv (r9 structure, occupancy 5 blocks/CU) ----------------
// out = relu([agg|x] @ Wcat^T + bl) (+ optional fused LN), fp32 out.
// Phases 0,1: x self-half staged in LDS (32 KB). Phases 2,3: agg from af frags.
// B fragments direct from pre-permuted wp (L2-resident).
__global__ __launch_bounds__(256, 5) void conv_mfma_kernel(
    const float* __restrict__ xln, const ushort* __restrict__ af,
    const ushort* __restrict__ wp, const float* __restrict__ bl,
    const float* __restrict__ lng, const float* __restrict__ lnb,
    float* __restrict__ out, int do_ln) {
  __shared__ ushort Xs[2][128 * 64];  // 32 KB
  const int t = threadIdx.x;
  const int lane = t & 63;
  const int wv = t >> 6;
  const int l15 = lane & 15;
  const int lq = lane >> 4;
  const int nbase = blockIdx.x * 128;

  f32x4 acc[2][8];
#pragma unroll
  for (int a = 0; a < 2; ++a)
#pragma unroll
    for (int b = 0; b < 8; ++b) acc[a][b] = (f32x4){0.f, 0.f, 0.f, 0.f};

  const int srow = t >> 1;
  const int sh2 = t & 1;
  const int gn_s = nbase + srow;
  const bool sval = gn_s < NN;
  char* lds_hi = (char*)&Xs[0][0];
  char* lds_lo = (char*)&Xs[1][0];
  const int sswz = (srow & 7) << 4;

  // ======== phases 0,1: x self-half (staged), W slice pk = ph+2 ========
#pragma unroll 1
  for (int ph = 0; ph < 2; ++ph) {
    if (ph) __syncthreads();
    const int kb = ph * 64;
#pragma unroll
    for (int i = 0; i < 8; ++i) {
      int qd = sh2 * 8 + i;
      float4 v = make_float4(0.f, 0.f, 0.f, 0.f);
      if (sval) v = *(const float4*)(xln + (size_t)gn_s * DIM + kb + qd * 4);
      int j = qd >> 3;
      int a = qd & 7;
      int inner = j * 64 + ((a < 4) ? a * 16 : (a - 4) * 16 + 8);
      int off = srow * 128 + inner;
      ushort4 hi, lo;
      hi.x = f2bf(v.x); lo.x = f2bf(v.x - bf2f(hi.x));
      hi.y = f2bf(v.y); lo.y = f2bf(v.y - bf2f(hi.y));
      hi.z = f2bf(v.z); lo.z = f2bf(v.z - bf2f(hi.z));
      hi.w = f2bf(v.w); lo.w = f2bf(v.w - bf2f(hi.w));
      *(ushort4*)(lds_hi + (off ^ sswz)) = hi;
      *(ushort4*)(lds_lo + (off ^ sswz)) = lo;
    }
    __syncthreads();
    const int pk = ph + 2;  // wr half of Wcat
#pragma unroll
    for (int j = 0; j < 2; ++j) {
      short8_t ahi[2], alo[2];
#pragma unroll
      for (int nt = 0; nt < 2; ++nt) {
        int row = wv * 32 + nt * 16 + l15;
        int off = row * 128 + j * 64 + lq * 16;
        int sw = (row & 7) << 4;
        ahi[nt] = *(short8_t*)(lds_hi + (off ^ sw));
        alo[nt] = *(short8_t*)(lds_lo + (off ^ sw));
      }
#pragma unroll
      for (int ht = 0; ht < 8; ++ht) {
        short8_t bhi = *(const short8_t*)(wp + (((pk * 2 + 0) * 2 + j) * 8 + ht) * 512 + lane * 8);
        short8_t blo = *(const short8_t*)(wp + (((pk * 2 + 1) * 2 + j) * 8 + ht) * 512 + lane * 8);
        acc[0][ht] = __builtin_amdgcn_mfma_f32_16x16x32_bf16(ahi[0], bhi, acc[0][ht], 0, 0, 0);
        acc[1][ht] = __builtin_amdgcn_mfma_f32_16x16x32_bf16(ahi[1], bhi, acc[1][ht], 0, 0, 0);
        acc[0][ht] = __builtin_amdgcn_mfma_f32_16x16x32_bf16(alo[0], bhi, acc[0][ht], 0, 0, 0);
        acc[1][ht] = __builtin_amdgcn_mfma_f32_16x16x32_bf16(alo[1], bhi, acc[1][ht], 0, 0, 0);
        acc[0][ht] = __builtin_amdgcn_mfma_f32_16x16x32_bf16(ahi[0], blo, acc[0][ht], 0, 0, 0);
        acc[1][ht] = __builtin_amdgcn_mfma_f32_16x16x32_bf16(ahi[1], blo, acc[1][ht], 0, 0, 0);
      }
    }
  }

  // ======== phases 2,3: agg half direct from fragments, W slice pk = ph-2 ====
  const int gblk = blockIdx.x * 8 + wv * 2;
#pragma unroll 1
  for (int ph = 2; ph < 4; ++ph) {
    const int pk = ph - 2;  // wl half of Wcat
#pragma unroll
    for (int j = 0; j < 2; ++j) {
      int jb = (ph & 1) * 2 + j;
      short8_t ahi[2], alo[2];
#pragma unroll
      for (int nt = 0; nt < 2; ++nt) {
        int g = gblk + nt;
        if (g < NGRP) {
          size_t base = (((size_t)g * 4 + jb) * 64 + lane) * 16;
          ahi[nt] = *(const short8_t*)(af + base);
          alo[nt] = *(const short8_t*)(af + base + 8);
        } else {
          ahi[nt] = (short8_t){0, 0, 0, 0, 0, 0, 0, 0};
          alo[nt] = (short8_t){0, 0, 0, 0, 0, 0, 0, 0};
        }
      }
#pragma unroll
      for (int ht = 0; ht < 8; ++ht) {
        short8_t bhi = *(const short8_t*)(wp + (((pk * 2 + 0) * 2 + j) * 8 + ht) * 512 + lane * 8);
        short8_t blo = *(const short8_t*)(wp + (((pk * 2 + 1) * 2 + j) * 8 + ht) * 512 + lane * 8);
        acc[0][ht] = __builtin_amdgcn_mfma_f32_16x16x32_bf16(ahi[0], bhi, acc[0][ht], 0, 0, 0);
        acc[1][ht] = __builtin_amdgcn_mfma_f32_16x16x32_bf16(ahi[1], bhi, acc[1][ht], 0, 0, 0);
        acc[0][ht] = __builtin_amdgcn_mfma_f32_16x16x32_bf16(alo[0], bhi, acc[0][ht], 0, 0, 0);
        acc[1][ht] = __builtin_amdgcn_mfma_f32_16x16x32_bf16(alo[1], bhi, acc[1][ht], 0, 0, 0);
        acc[0][ht] = __builtin_amdgcn_mfma_f32_16x16x32_bf16(ahi[0], blo, acc[0][ht], 0, 0, 0);
        acc[1][ht] = __builtin_amdgcn_mfma_f32_16x16x32_bf16(ahi[1], blo, acc[1][ht], 0, 0, 0);
      }
    }
  }

  // ======== epilogue: bias + relu (+ fused LN), fp32 row-major store ========
#pragma unroll
  for (int ht = 0; ht < 8; ++ht) {
    float bv = bl[ht * 16 + l15];
#pragma unroll
    for (int nt = 0; nt < 2; ++nt)
#pragma unroll
      for (int r = 0; r < 4; ++r) acc[nt][ht][r] = fmaxf(acc[nt][ht][r] + bv, 0.f);
  }
  if (do_ln) {
    float gg[8], bb[8];
#pragma unroll
    for (int ht = 0; ht < 8; ++ht) {
      gg[ht] = lng[ht * 16 + l15];
      bb[ht] = lnb[ht * 16 + l15];
    }
#pragma unroll
    for (int nt = 0; nt < 2; ++nt) {
#pragma unroll
      for (int r = 0; r < 4; ++r) {
        float s = 0.f, sq = 0.f;
#pragma unroll
        for (int ht = 0; ht < 8; ++ht) {
          float v = acc[nt][ht][r];
          s += v;
          sq += v * v;
        }
#pragma unroll
        for (int msk = 1; msk < 16; msk <<= 1) {
          s += __shfl_xor(s, msk);
          sq += __shfl_xor(sq, msk);
        }
        float m = s * (1.0f / 128.0f);
        float var = sq * (1.0f / 128.0f) - m * m;
        float rstd = rsqrtf(var + 1e-5f);
        int node = nbase + wv * 32 + nt * 16 + lq * 4 + r;
        if (node < NN) {
#pragma unroll
          for (int ht = 0; ht < 8; ++ht)
            out[(size_t)node * DIM + ht * 16 + l15] =
                (acc[nt][ht][r] - m) * rstd * gg[ht] + bb[ht];
        }
      }
    }
  } else {
#pragma unroll
    for (int nt = 0; nt < 2; ++nt) {
#pragma unroll
      for (int r = 0; r < 4; ++r) {
        int node = nbase + wv * 32 + nt * 16 + lq * 4 + r;
        if (node < NN) {
#pragma unroll
          for (int ht = 0; ht < 8; ++ht)
            out[(size_t)node * DIM + ht * 16 + l15] = acc[nt][ht][r];
        }
      }
    }
  }
}

// ---------------- mean pool over sorted batch ----------------
#define PCHUNK 128
__global__ __launch_bounds__(128) void pool_kernel(const float* __restrict__ x,
                                                   const int* __restrict__ batch,
                                                   float* __restrict__ pool,
                                                   float* __restrict__ cnt) {
  int f = threadIdx.x;
  int n0 = blockIdx.x * PCHUNK;
  float acc = 0.f;
  int cur = batch[n0];
  int runlen = 0;
  for (int i = 0; i < PCHUNK; ++i) {
    int n = n0 + i;
    if (n >= NN) break;
    int bg = batch[n];
    if (bg != cur) {
      atomicAdd(&pool[cur * DIM + f], acc);
      if (f == 0) atomicAdd(&cnt[cur], (float)runlen);
      acc = 0.f;
      runlen = 0;
      cur = bg;
    }
    acc += x[(size_t)n * DIM + f];
    runlen++;
  }
  if (runlen > 0) {
    atomicAdd(&pool[cur * DIM + f], acc);
    if (f == 0) atomicAdd(&cnt[cur], (float)runlen);
  }
}

// ---------------- MLP head ----------------
__global__ __launch_bounds__(128) void head_kernel(
    const float* __restrict__ pool, const float* __restrict__ cnt,
    const float* __restrict__ w1, const float* __restrict__ b1,
    const float* __restrict__ w2, const float* __restrict__ b2,
    float* __restrict__ out) {
  __shared__ float gsh[128];
  __shared__ float h[64];
  int g = blockIdx.x;
  int t = threadIdx.x;
  float ic = 1.0f / fmaxf(cnt[g], 1.0f);
  gsh[t] = pool[g * DIM + t] * ic;
  __syncthreads();
  if (t < 64) {
    float a = b1[t];
#pragma unroll 8
    for (int k = 0; k < 128; ++k) a += gsh[k] * w1[t * 128 + k];
    h[t] = fmaxf(a, 0.f);
  }
  __syncthreads();
  if (t < 2) {
    float a = b2[t];
#pragma unroll
    for (int k = 0; k < 64; ++k) a += h[k] * w2[t * 64 + k];
    out[g * 2 + t] = a;
  }
}

extern "C" void kernel_launch(void* const* d_in, const int* in_sizes, int n_in,
                              void* d_out, int out_size, void* d_ws, size_t ws_size,
                              hipStream_t stream) {
  const int* x_idx = (const int*)d_in[0];
  const int* eidx = (const int*)d_in[1];
  const int* batch = (const int*)d_in[2];
  const float* emb = (const float*)d_in[3];
  const float* ln0g = (const float*)d_in[4];
  const float* ln0b = (const float*)d_in[5];
  const float* w0l = (const float*)d_in[6];
  const float* b0l = (const float*)d_in[7];
  const float* w0r = (const float*)d_in[8];
  const float* ln1g = (const float*)d_in[9];
  const float* ln1b = (const float*)d_in[10];
  const float* w1l = (const float*)d_in[11];
  const float* b1l = (const float*)d_in[12];
  const float* w1r = (const float*)d_in[13];
  const float* mw1 = (const float*)d_in[14];
  const float* mb1 = (const float*)d_in[15];
  const float* mw2 = (const float*)d_in[16];
  const float* mb2 = (const float*)d_in[17];
  float* out = (float*)d_out;

  float* ws = (float*)d_ws;
  float* x = ws;                                   // NN*DIM fp32
  ushort* af = (ushort*)(x + (size_t)NN * DIM);    // NN*DIM*2 ushort (frag agg)
  float* pool = (float*)(af + (size_t)NN * DIM * 2);  // NG*DIM
  float* cnt = pool + (size_t)NG * DIM;            // NG
  int* degi = (int*)(cnt + NG);                    // NN (contig for one memset)
  int* excl = degi + NN;                           // NN
  int* row_off = excl + NN;                        // NN+1
  int* cursor = row_off + NN + 1;                  // NN
  int* bsum = cursor + NN;                         // 512
  int* csr_src = bsum + 512;                       // NE
  ushort* wp0 = (ushort*)(csr_src + NE);           // 65536 ushort each
  ushort* wp1 = wp0 + 65536;

  const int* src = eidx;
  const int* dst = eidx + NE;

  // one memset: pool + cnt + degi are contiguous
  hipMemsetAsync(pool, 0, ((size_t)NG * DIM + NG + NN) * sizeof(float), stream);

  deg_int_kernel<<<FILL_NB, 256, 0, stream>>>(dst, degi);
  scan1_kernel<<<NB_SCAN, 256, 0, stream>>>(degi, excl, bsum);
  scan23_kernel<<<NB_SCAN, 256, 0, stream>>>(excl, bsum, row_off, cursor);
  mega_kernel<<<FILL_NB + 2 * PREP_NB + EMB_NB, 256, 0, stream>>>(
      src, dst, cursor, csr_src, w0l, w0r, wp0, w1l, w1r, wp1, x_idx, emb, ln0g, ln0b, x);

  // layer 0 (conv epilogue applies LN1, in-place x)
  gather_mean_kernel<<<(NN + 7) / 8, 256, 0, stream>>>(row_off, csr_src, x, af);
  conv_mfma_kernel<<<(NN + 127) / 128, 256, 0, stream>>>(x, af, wp0, b0l, ln1g, ln1b, x, 1);
  // layer 1 (plain relu epilogue, in-place x)
  gather_mean_kernel<<<(NN + 7) / 8, 256, 0, stream>>>(row_off, csr_src, x, af);
  conv_mfma_kernel<<<(NN + 127) / 128, 256, 0, stream>>>(x, af, wp1, b1l, (const float*)0, (const float*)0, x, 0);

  pool_kernel<<<(NN + PCHUNK - 1) / PCHUNK, 128, 0, stream>>>(x, batch, pool, cnt);
  head_kernel<<<NG, 128, 0, stream>>>(pool, cnt, mw1, mb1, mw2, mb2, out);
}

// Round 13
// 440.241 us; speedup vs baseline: 1.3125x; 1.2444x over previous
//
#include <hip/hip_runtime.h>

#define NN 100000
#define NE 600000
#define DIM 128
#define NG 256
#define NGRP 6250   // NN/16
#define NB_SCAN 391  // ceil(NN/256)
#define FILL_NB 2344 // ceil(NE/256)
#define PREP_NB 128
#define EMB_NB 25000 // NN/4

typedef __attribute__((ext_vector_type(8))) short short8_t;
typedef __attribute__((ext_vector_type(4))) float f32x4;

__device__ __forceinline__ ushort f2bf(float f) {
  unsigned u = __float_as_uint(f);
  unsigned r = (u + 0x7fffu + ((u >> 16) & 1u)) >> 16;
  return (ushort)r;
}
__device__ __forceinline__ float bf2f(ushort h) {
  return __uint_as_float(((unsigned)h) << 16);
}

// ---------------- CSR: degree ----------------
__global__ __launch_bounds__(256) void deg_int_kernel(const int* __restrict__ dst,
                                                      int* __restrict__ degi) {
  int e = blockIdx.x * 256 + threadIdx.x;
  if (e < NE) atomicAdd(degi + dst[e], 1);
}

// ---------------- CSR: per-block scan ----------------
__global__ __launch_bounds__(256) void scan1_kernel(const int* __restrict__ degi,
                                                    int* __restrict__ excl,
                                                    int* __restrict__ bsum) {
  __shared__ int tmp[256];
  int t = threadIdx.x;
  int i = blockIdx.x * 256 + t;
  int v = (i < NN) ? degi[i] : 0;
  int val = v;
  tmp[t] = val;
  __syncthreads();
  for (int off = 1; off < 256; off <<= 1) {
    int add = (t >= off) ? tmp[t - off] : 0;
    __syncthreads();
    val += add;
    tmp[t] = val;
    __syncthreads();
  }
  if (i < NN) excl[i] = val - v;
  if (t == 255) bsum[blockIdx.x] = val;
}

// ---------------- CSR: block-offset + row_off + cursor ----------------
__global__ __launch_bounds__(256) void scan23_kernel(const int* __restrict__ excl,
                                                     const int* __restrict__ bsum,
                                                     int* __restrict__ row_off,
                                                     int* __restrict__ cursor) {
  __shared__ int sh[256];
  int blk = blockIdx.x;
  int t = threadIdx.x;
  int partial = 0;
  for (int j = t; j < blk; j += 256) partial += bsum[j];
  sh[t] = partial;
  __syncthreads();
  for (int off = 128; off; off >>= 1) {
    if (t < off) sh[t] += sh[t + off];
    __syncthreads();
  }
  int base = sh[0];
  int i = blk * 256 + t;
  if (i < NN) {
    int r = excl[i] + base;
    row_off[i] = r;
    cursor[i] = r;
  }
  if (i == NN) row_off[NN] = NE;
}

// ---------------- device bodies for the mega kernel ----------------
__device__ __forceinline__ void fill_body(int bid, int t, const int* __restrict__ src,
                                          const int* __restrict__ dst,
                                          int* __restrict__ cursor,
                                          int* __restrict__ csr_src) {
  int e = bid * 256 + t;
  if (e < NE) {
    int d = dst[e];
    int slot = atomicAdd(cursor + d, 1);
    csr_src[slot] = src[e];
  }
}

// wp layout: [p][hl][j][ht][lane][8]; k = p*64 + j*32 + lq*4 + (e&3) + 16*(e>>2);
// k<128 -> wl (agg term, p=0,1), k>=128 -> wr (self term, p=2,3).
__device__ __forceinline__ void prep_body(int idx, const float* __restrict__ wl,
                                          const float* __restrict__ wr,
                                          ushort* __restrict__ wp) {
  int e = idx & 7;
  int lane = (idx >> 3) & 63;
  int ht = (idx >> 9) & 7;
  int j = (idx >> 12) & 1;
  int p = (idx >> 13) & 3;
  int h = ht * 16 + (lane & 15);
  int lq = lane >> 4;
  int k = p * 64 + j * 32 + lq * 4 + (e & 3) + 16 * (e >> 2);
  float v = (k < 128) ? wl[h * 128 + k] : wr[h * 128 + (k - 128)];
  ushort hi = f2bf(v);
  ushort lo = f2bf(v - bf2f(hi));
  wp[(((p * 2 + 0) * 2 + j) * 8 + ht) * 512 + lane * 8 + e] = hi;
  wp[(((p * 2 + 1) * 2 + j) * 8 + ht) * 512 + lane * 8 + e] = lo;
}

__device__ __forceinline__ void embed_body(int bid, int t, const int* __restrict__ x_idx,
                                           const float* __restrict__ emb,
                                           const float* __restrict__ g,
                                           const float* __restrict__ b,
                                           float* __restrict__ out) {
  int wave = t >> 6;
  int lane = t & 63;
  int n = bid * 4 + wave;
  if (n >= NN) return;
  int idx = x_idx[n];
  float2 v = ((const float2*)(emb + (size_t)idx * DIM))[lane];
  float s = v.x + v.y;
  float sq = v.x * v.x + v.y * v.y;
  for (int off = 32; off; off >>= 1) {
    s += __shfl_xor(s, off);
    sq += __shfl_xor(sq, off);
  }
  float m = s * (1.0f / 128.0f);
  float var = sq * (1.0f / 128.0f) - m * m;
  float r = rsqrtf(var + 1e-5f);
  float2 gg = ((const float2*)g)[lane];
  float2 bb = ((const float2*)b)[lane];
  float2 o;
  o.x = (v.x - m) * r * gg.x + bb.x;
  o.y = (v.y - m) * r * gg.y + bb.y;
  ((float2*)(out + (size_t)n * DIM))[lane] = o;
}

// ---------------- mega kernel: fill | prep_w x2 | embed_ln ----------------
__global__ __launch_bounds__(256) void mega_kernel(
    const int* __restrict__ src, const int* __restrict__ dst,
    int* __restrict__ cursor, int* __restrict__ csr_src,
    const float* __restrict__ w0l, const float* __restrict__ w0r, ushort* __restrict__ wp0,
    const float* __restrict__ w1l, const float* __restrict__ w1r, ushort* __restrict__ wp1,
    const int* __restrict__ x_idx, const float* __restrict__ emb,
    const float* __restrict__ ln0g, const float* __restrict__ ln0b,
    float* __restrict__ x) {
  int bid = blockIdx.x;
  int t = threadIdx.x;
  if (bid < FILL_NB) {
    fill_body(bid, t, src, dst, cursor, csr_src);
  } else if (bid < FILL_NB + PREP_NB) {
    prep_body((bid - FILL_NB) * 256 + t, w0l, w0r, wp0);
  } else if (bid < FILL_NB + 2 * PREP_NB) {
    prep_body((bid - FILL_NB - PREP_NB) * 256 + t, w1l, w1r, wp1);
  } else {
    embed_body(bid - FILL_NB - 2 * PREP_NB, t, x_idx, emb, ln0g, ln0b, x);
  }
}

// ---------------- gather mean -> fragment-layout agg ----------------
// af layout (ushort): [g16][jb(4)][lane(64)][hl(2)][e(8)], lane=(lq*16+l15),
// node n = g16*16+l15, k = jb*32 + lq*4 + (e&3) + 16*(e>>2).
__global__ __launch_bounds__(256) void gather_mean_kernel(
    const int* __restrict__ row_off, const int* __restrict__ csr_src,
    const float* __restrict__ x, ushort* __restrict__ af) {
  int t = threadIdx.x;
  int q = t & 31;
  int node = blockIdx.x * 8 + (t >> 5);
  if (node >= NN) return;
  int beg = row_off[node], end = row_off[node + 1];
  float4 acc = make_float4(0.f, 0.f, 0.f, 0.f);
  for (int e = beg; e < end; ++e) {
    int s = csr_src[e];
    float4 v = ((const float4*)(x + (size_t)s * DIM))[q];
    acc.x += v.x; acc.y += v.y; acc.z += v.z; acc.w += v.w;
  }
  float sc = 1.0f / fmaxf((float)(end - beg), 1.0f);
  acc.x *= sc; acc.y *= sc; acc.z *= sc; acc.w *= sc;
  ushort4 hi, lo;
  hi.x = f2bf(acc.x); lo.x = f2bf(acc.x - bf2f(hi.x));
  hi.y = f2bf(acc.y); lo.y = f2bf(acc.y - bf2f(hi.y));
  hi.z = f2bf(acc.z); lo.z = f2bf(acc.z - bf2f(hi.z));
  hi.w = f2bf(acc.w); lo.w = f2bf(acc.w - bf2f(hi.w));
  int g = node >> 4, l15n = node & 15;
  int jb = q >> 3, lqw = q & 3, ebase = q & 4;
  size_t base = (((size_t)g * 4 + jb) * 64 + lqw * 16 + l15n) * 16;
  *(ushort4*)(af + base + ebase) = hi;
  *(ushort4*)(af + base + 8 + ebase) = lo;
}

// ---------------- SAGE conv (r9 structure, 4 blocks/CU: no-spill TLP test) -----
// out = relu([agg|x] @ Wcat^T + bl) (+ optional fused LN), fp32 out.
// Phases 0,1: x self-half staged in LDS (32 KB). Phases 2,3: agg from af frags.
// B fragments direct from pre-permuted wp (L2-resident).
// launch_bounds(256,4): 4 blocks/CU, VGPR budget 128 >= ~88 needed -> no spill.
__global__ __launch_bounds__(256, 4) void conv_mfma_kernel(
    const float* __restrict__ xln, const ushort* __restrict__ af,
    const ushort* __restrict__ wp, const float* __restrict__ bl,
    const float* __restrict__ lng, const float* __restrict__ lnb,
    float* __restrict__ out, int do_ln) {
  __shared__ ushort Xs[2][128 * 64];  // 32 KB
  const int t = threadIdx.x;
  const int lane = t & 63;
  const int wv = t >> 6;
  const int l15 = lane & 15;
  const int lq = lane >> 4;
  const int nbase = blockIdx.x * 128;

  f32x4 acc[2][8];
#pragma unroll
  for (int a = 0; a < 2; ++a)
#pragma unroll
    for (int b = 0; b < 8; ++b) acc[a][b] = (f32x4){0.f, 0.f, 0.f, 0.f};

  const int srow = t >> 1;
  const int sh2 = t & 1;
  const int gn_s = nbase + srow;
  const bool sval = gn_s < NN;
  char* lds_hi = (char*)&Xs[0][0];
  char* lds_lo = (char*)&Xs[1][0];
  const int sswz = (srow & 7) << 4;

  // ======== phases 0,1: x self-half (staged), W slice pk = ph+2 ========
#pragma unroll 1
  for (int ph = 0; ph < 2; ++ph) {
    if (ph) __syncthreads();
    const int kb = ph * 64;
#pragma unroll
    for (int i = 0; i < 8; ++i) {
      int qd = sh2 * 8 + i;
      float4 v = make_float4(0.f, 0.f, 0.f, 0.f);
      if (sval) v = *(const float4*)(xln + (size_t)gn_s * DIM + kb + qd * 4);
      int j = qd >> 3;
      int a = qd & 7;
      int inner = j * 64 + ((a < 4) ? a * 16 : (a - 4) * 16 + 8);
      int off = srow * 128 + inner;
      ushort4 hi, lo;
      hi.x = f2bf(v.x); lo.x = f2bf(v.x - bf2f(hi.x));
      hi.y = f2bf(v.y); lo.y = f2bf(v.y - bf2f(hi.y));
      hi.z = f2bf(v.z); lo.z = f2bf(v.z - bf2f(hi.z));
      hi.w = f2bf(v.w); lo.w = f2bf(v.w - bf2f(hi.w));
      *(ushort4*)(lds_hi + (off ^ sswz)) = hi;
      *(ushort4*)(lds_lo + (off ^ sswz)) = lo;
    }
    __syncthreads();
    const int pk = ph + 2;  // wr half of Wcat
#pragma unroll
    for (int j = 0; j < 2; ++j) {
      short8_t ahi[2], alo[2];
#pragma unroll
      for (int nt = 0; nt < 2; ++nt) {
        int row = wv * 32 + nt * 16 + l15;
        int off = row * 128 + j * 64 + lq * 16;
        int sw = (row & 7) << 4;
        ahi[nt] = *(short8_t*)(lds_hi + (off ^ sw));
        alo[nt] = *(short8_t*)(lds_lo + (off ^ sw));
      }
#pragma unroll
      for (int ht = 0; ht < 8; ++ht) {
        short8_t bhi = *(const short8_t*)(wp + (((pk * 2 + 0) * 2 + j) * 8 + ht) * 512 + lane * 8);
        short8_t blo = *(const short8_t*)(wp + (((pk * 2 + 1) * 2 + j) * 8 + ht) * 512 + lane * 8);
        acc[0][ht] = __builtin_amdgcn_mfma_f32_16x16x32_bf16(ahi[0], bhi, acc[0][ht], 0, 0, 0);
        acc[1][ht] = __builtin_amdgcn_mfma_f32_16x16x32_bf16(ahi[1], bhi, acc[1][ht], 0, 0, 0);
        acc[0][ht] = __builtin_amdgcn_mfma_f32_16x16x32_bf16(alo[0], bhi, acc[0][ht], 0, 0, 0);
        acc[1][ht] = __builtin_amdgcn_mfma_f32_16x16x32_bf16(alo[1], bhi, acc[1][ht], 0, 0, 0);
        acc[0][ht] = __builtin_amdgcn_mfma_f32_16x16x32_bf16(ahi[0], blo, acc[0][ht], 0, 0, 0);
        acc[1][ht] = __builtin_amdgcn_mfma_f32_16x16x32_bf16(ahi[1], blo, acc[1][ht], 0, 0, 0);
      }
    }
  }

  // ======== phases 2,3: agg half direct from fragments, W slice pk = ph-2 ====
  const int gblk = blockIdx.x * 8 + wv * 2;
#pragma unroll 1
  for (int ph = 2; ph < 4; ++ph) {
    const int pk = ph - 2;  // wl half of Wcat
#pragma unroll
    for (int j = 0; j < 2; ++j) {
      int jb = (ph & 1) * 2 + j;
      short8_t ahi[2], alo[2];
#pragma unroll
      for (int nt = 0; nt < 2; ++nt) {
        int g = gblk + nt;
        if (g < NGRP) {
          size_t base = (((size_t)g * 4 + jb) * 64 + lane) * 16;
          ahi[nt] = *(const short8_t*)(af + base);
          alo[nt] = *(const short8_t*)(af + base + 8);
        } else {
          ahi[nt] = (short8_t){0, 0, 0, 0, 0, 0, 0, 0};
          alo[nt] = (short8_t){0, 0, 0, 0, 0, 0, 0, 0};
        }
      }
#pragma unroll
      for (int ht = 0; ht < 8; ++ht) {
        short8_t bhi = *(const short8_t*)(wp + (((pk * 2 + 0) * 2 + j) * 8 + ht) * 512 + lane * 8);
        short8_t blo = *(const short8_t*)(wp + (((pk * 2 + 1) * 2 + j) * 8 + ht) * 512 + lane * 8);
        acc[0][ht] = __builtin_amdgcn_mfma_f32_16x16x32_bf16(ahi[0], bhi, acc[0][ht], 0, 0, 0);
        acc[1][ht] = __builtin_amdgcn_mfma_f32_16x16x32_bf16(ahi[1], bhi, acc[1][ht], 0, 0, 0);
        acc[0][ht] = __builtin_amdgcn_mfma_f32_16x16x32_bf16(alo[0], bhi, acc[0][ht], 0, 0, 0);
        acc[1][ht] = __builtin_amdgcn_mfma_f32_16x16x32_bf16(alo[1], bhi, acc[1][ht], 0, 0, 0);
        acc[0][ht] = __builtin_amdgcn_mfma_f32_16x16x32_bf16(ahi[0], blo, acc[0][ht], 0, 0, 0);
        acc[1][ht] = __builtin_amdgcn_mfma_f32_16x16x32_bf16(ahi[1], blo, acc[1][ht], 0, 0, 0);
      }
    }
  }

  // ======== epilogue: bias + relu (+ fused LN), fp32 row-major store ========
#pragma unroll
  for (int ht = 0; ht < 8; ++ht) {
    float bv = bl[ht * 16 + l15];
#pragma unroll
    for (int nt = 0; nt < 2; ++nt)
#pragma unroll
      for (int r = 0; r < 4; ++r) acc[nt][ht][r] = fmaxf(acc[nt][ht][r] + bv, 0.f);
  }
  if (do_ln) {
    float gg[8], bb[8];
#pragma unroll
    for (int ht = 0; ht < 8; ++ht) {
      gg[ht] = lng[ht * 16 + l15];
      bb[ht] = lnb[ht * 16 + l15];
    }
#pragma unroll
    for (int nt = 0; nt < 2; ++nt) {
#pragma unroll
      for (int r = 0; r < 4; ++r) {
        float s = 0.f, sq = 0.f;
#pragma unroll
        for (int ht = 0; ht < 8; ++ht) {
          float v = acc[nt][ht][r];
          s += v;
          sq += v * v;
        }
#pragma unroll
        for (int msk = 1; msk < 16; msk <<= 1) {
          s += __shfl_xor(s, msk);
          sq += __shfl_xor(sq, msk);
        }
        float m = s * (1.0f / 128.0f);
        float var = sq * (1.0f / 128.0f) - m * m;
        float rstd = rsqrtf(var + 1e-5f);
        int node = nbase + wv * 32 + nt * 16 + lq * 4 + r;
        if (node < NN) {
#pragma unroll
          for (int ht = 0; ht < 8; ++ht)
            out[(size_t)node * DIM + ht * 16 + l15] =
                (acc[nt][ht][r] - m) * rstd * gg[ht] + bb[ht];
        }
      }
    }
  } else {
#pragma unroll
    for (int nt = 0; nt < 2; ++nt) {
#pragma unroll
      for (int r = 0; r < 4; ++r) {
        int node = nbase + wv * 32 + nt * 16 + lq * 4 + r;
        if (node < NN) {
#pragma unroll
          for (int ht = 0; ht < 8; ++ht)
            out[(size_t)node * DIM + ht * 16 + l15] = acc[nt][ht][r];
        }
      }
    }
  }
}

// ---------------- mean pool over sorted batch ----------------
#define PCHUNK 128
__global__ __launch_bounds__(128) void pool_kernel(const float* __restrict__ x,
                                                   const int* __restrict__ batch,
                                                   float* __restrict__ pool,
                                                   float* __restrict__ cnt) {
  int f = threadIdx.x;
  int n0 = blockIdx.x * PCHUNK;
  float acc = 0.f;
  int cur = batch[n0];
  int runlen = 0;
  for (int i = 0; i < PCHUNK; ++i) {
    int n = n0 + i;
    if (n >= NN) break;
    int bg = batch[n];
    if (bg != cur) {
      atomicAdd(&pool[cur * DIM + f], acc);
      if (f == 0) atomicAdd(&cnt[cur], (float)runlen);
      acc = 0.f;
      runlen = 0;
      cur = bg;
    }
    acc += x[(size_t)n * DIM + f];
    runlen++;
  }
  if (runlen > 0) {
    atomicAdd(&pool[cur * DIM + f], acc);
    if (f == 0) atomicAdd(&cnt[cur], (float)runlen);
  }
}

// ---------------- MLP head ----------------
__global__ __launch_bounds__(128) void head_kernel(
    const float* __restrict__ pool, const float* __restrict__ cnt,
    const float* __restrict__ w1, const float* __restrict__ b1,
    const float* __restrict__ w2, const float* __restrict__ b2,
    float* __restrict__ out) {
  __shared__ float gsh[128];
  __shared__ float h[64];
  int g = blockIdx.x;
  int t = threadIdx.x;
  float ic = 1.0f / fmaxf(cnt[g], 1.0f);
  gsh[t] = pool[g * DIM + t] * ic;
  __syncthreads();
  if (t < 64) {
    float a = b1[t];
#pragma unroll 8
    for (int k = 0; k < 128; ++k) a += gsh[k] * w1[t * 128 + k];
    h[t] = fmaxf(a, 0.f);
  }
  __syncthreads();
  if (t < 2) {
    float a = b2[t];
#pragma unroll
    for (int k = 0; k < 64; ++k) a += h[k] * w2[t * 64 + k];
    out[g * 2 + t] = a;
  }
}

extern "C" void kernel_launch(void* const* d_in, const int* in_sizes, int n_in,
                              void* d_out, int out_size, void* d_ws, size_t ws_size,
                              hipStream_t stream) {
  const int* x_idx = (const int*)d_in[0];
  const int* eidx = (const int*)d_in[1];
  const int* batch = (const int*)d_in[2];
  const float* emb = (const float*)d_in[3];
  const float* ln0g = (const float*)d_in[4];
  const float* ln0b = (const float*)d_in[5];
  const float* w0l = (const float*)d_in[6];
  const float* b0l = (const float*)d_in[7];
  const float* w0r = (const float*)d_in[8];
  const float* ln1g = (const float*)d_in[9];
  const float* ln1b = (const float*)d_in[10];
  const float* w1l = (const float*)d_in[11];
  const float* b1l = (const float*)d_in[12];
  const float* w1r = (const float*)d_in[13];
  const float* mw1 = (const float*)d_in[14];
  const float* mb1 = (const float*)d_in[15];
  const float* mw2 = (const float*)d_in[16];
  const float* mb2 = (const float*)d_in[17];
  float* out = (float*)d_out;

  float* ws = (float*)d_ws;
  float* x = ws;                                   // NN*DIM fp32
  ushort* af = (ushort*)(x + (size_t)NN * DIM);    // NN*DIM*2 ushort (frag agg)
  float* pool = (float*)(af + (size_t)NN * DIM * 2);  // NG*DIM
  float* cnt = pool + (size_t)NG * DIM;            // NG
  int* degi = (int*)(cnt + NG);                    // NN (contig for one memset)
  int* excl = degi + NN;                           // NN
  int* row_off = excl + NN;                        // NN+1
  int* cursor = row_off + NN + 1;                  // NN
  int* bsum = cursor + NN;                         // 512
  int* csr_src = bsum + 512;                       // NE
  ushort* wp0 = (ushort*)(csr_src + NE);           // 65536 ushort each
  ushort* wp1 = wp0 + 65536;

  const int* src = eidx;
  const int* dst = eidx + NE;

  // one memset: pool + cnt + degi are contiguous
  hipMemsetAsync(pool, 0, ((size_t)NG * DIM + NG + NN) * sizeof(float), stream);

  deg_int_kernel<<<FILL_NB, 256, 0, stream>>>(dst, degi);
  scan1_kernel<<<NB_SCAN, 256, 0, stream>>>(degi, excl, bsum);
  scan23_kernel<<<NB_SCAN, 256, 0, stream>>>(excl, bsum, row_off, cursor);
  mega_kernel<<<FILL_NB + 2 * PREP_NB + EMB_NB, 256, 0, stream>>>(
      src, dst, cursor, csr_src, w0l, w0r, wp0, w1l, w1r, wp1, x_idx, emb, ln0g, ln0b, x);

  // layer 0 (conv epilogue applies LN1, in-place x)
  gather_mean_kernel<<<(NN + 7) / 8, 256, 0, stream>>>(row_off, csr_src, x, af);
  conv_mfma_kernel<<<(NN + 127) / 128, 256, 0, stream>>>(x, af, wp0, b0l, ln1g, ln1b, x, 1);
  // layer 1 (plain relu epilogue, in-place x)
  gather_mean_kernel<<<(NN + 7) / 8, 256, 0, stream>>>(row_off, csr_src, x, af);
  conv_mfma_kernel<<<(NN + 127) / 128, 256, 0, stream>>>(x, af, wp1, b1l, (const float*)0, (const float*)0, x, 0);

  pool_kernel<<<(NN + PCHUNK - 1) / PCHUNK, 128, 0, stream>>>(x, batch, pool, cnt);
  head_kernel<<<NG, 128, 0, stream>>>(pool, cnt, mw1, mb1, mw2, mb2, out);
}

// Round 14
// 410.409 us; speedup vs baseline: 1.4079x; 1.0727x over previous
//
#include <hip/hip_runtime.h>

#define NN 100000
#define NE 600000
#define DIM 128
#define NG 256
#define NGRP 6250   // NN/16
#define NB_SCAN 391  // ceil(NN/256)
#define FILL_NB 2344 // ceil(NE/256)
#define PREP_NB 128
#define EMB_NB 25000 // NN/4

typedef __attribute__((ext_vector_type(8))) short short8_t;
typedef __attribute__((ext_vector_type(4))) float f32x4;

__device__ __forceinline__ ushort f2bf(float f) {
  unsigned u = __float_as_uint(f);
  unsigned r = (u + 0x7fffu + ((u >> 16) & 1u)) >> 16;
  return (ushort)r;
}
__device__ __forceinline__ float bf2f(ushort h) {
  return __uint_as_float(((unsigned)h) << 16);
}

// ---------------- CSR: degree ----------------
__global__ __launch_bounds__(256) void deg_int_kernel(const int* __restrict__ dst,
                                                      int* __restrict__ degi) {
  int e = blockIdx.x * 256 + threadIdx.x;
  if (e < NE) atomicAdd(degi + dst[e], 1);
}

// ---------------- CSR: per-block scan ----------------
__global__ __launch_bounds__(256) void scan1_kernel(const int* __restrict__ degi,
                                                    int* __restrict__ excl,
                                                    int* __restrict__ bsum) {
  __shared__ int tmp[256];
  int t = threadIdx.x;
  int i = blockIdx.x * 256 + t;
  int v = (i < NN) ? degi[i] : 0;
  int val = v;
  tmp[t] = val;
  __syncthreads();
  for (int off = 1; off < 256; off <<= 1) {
    int add = (t >= off) ? tmp[t - off] : 0;
    __syncthreads();
    val += add;
    tmp[t] = val;
    __syncthreads();
  }
  if (i < NN) excl[i] = val - v;
  if (t == 255) bsum[blockIdx.x] = val;
}

// ---------------- CSR: block-offset + row_off + cursor ----------------
__global__ __launch_bounds__(256) void scan23_kernel(const int* __restrict__ excl,
                                                     const int* __restrict__ bsum,
                                                     int* __restrict__ row_off,
                                                     int* __restrict__ cursor) {
  __shared__ int sh[256];
  int blk = blockIdx.x;
  int t = threadIdx.x;
  int partial = 0;
  for (int j = t; j < blk; j += 256) partial += bsum[j];
  sh[t] = partial;
  __syncthreads();
  for (int off = 128; off; off >>= 1) {
    if (t < off) sh[t] += sh[t + off];
    __syncthreads();
  }
  int base = sh[0];
  int i = blk * 256 + t;
  if (i < NN) {
    int r = excl[i] + base;
    row_off[i] = r;
    cursor[i] = r;
  }
  if (i == NN) row_off[NN] = NE;
}

// ---------------- device bodies for the mega kernel ----------------
__device__ __forceinline__ void fill_body(int bid, int t, const int* __restrict__ src,
                                          const int* __restrict__ dst,
                                          int* __restrict__ cursor,
                                          int* __restrict__ csr_src) {
  int e = bid * 256 + t;
  if (e < NE) {
    int d = dst[e];
    int slot = atomicAdd(cursor + d, 1);
    csr_src[slot] = src[e];
  }
}

// wp layout: [p][hl][j][ht][lane][8]; k = p*64 + j*32 + lq*4 + (e&3) + 16*(e>>2);
// k<128 -> wl (agg term, p=0,1), k>=128 -> wr (self term, p=2,3).
__device__ __forceinline__ void prep_body(int idx, const float* __restrict__ wl,
                                          const float* __restrict__ wr,
                                          ushort* __restrict__ wp) {
  int e = idx & 7;
  int lane = (idx >> 3) & 63;
  int ht = (idx >> 9) & 7;
  int j = (idx >> 12) & 1;
  int p = (idx >> 13) & 3;
  int h = ht * 16 + (lane & 15);
  int lq = lane >> 4;
  int k = p * 64 + j * 32 + lq * 4 + (e & 3) + 16 * (e >> 2);
  float v = (k < 128) ? wl[h * 128 + k] : wr[h * 128 + (k - 128)];
  ushort hi = f2bf(v);
  ushort lo = f2bf(v - bf2f(hi));
  wp[(((p * 2 + 0) * 2 + j) * 8 + ht) * 512 + lane * 8 + e] = hi;
  wp[(((p * 2 + 1) * 2 + j) * 8 + ht) * 512 + lane * 8 + e] = lo;
}

__device__ __forceinline__ void embed_body(int bid, int t, const int* __restrict__ x_idx,
                                           const float* __restrict__ emb,
                                           const float* __restrict__ g,
                                           const float* __restrict__ b,
                                           float* __restrict__ out) {
  int wave = t >> 6;
  int lane = t & 63;
  int n = bid * 4 + wave;
  if (n >= NN) return;
  int idx = x_idx[n];
  float2 v = ((const float2*)(emb + (size_t)idx * DIM))[lane];
  float s = v.x + v.y;
  float sq = v.x * v.x + v.y * v.y;
  for (int off = 32; off; off >>= 1) {
    s += __shfl_xor(s, off);
    sq += __shfl_xor(sq, off);
  }
  float m = s * (1.0f / 128.0f);
  float var = sq * (1.0f / 128.0f) - m * m;
  float r = rsqrtf(var + 1e-5f);
  float2 gg = ((const float2*)g)[lane];
  float2 bb = ((const float2*)b)[lane];
  float2 o;
  o.x = (v.x - m) * r * gg.x + bb.x;
  o.y = (v.y - m) * r * gg.y + bb.y;
  ((float2*)(out + (size_t)n * DIM))[lane] = o;
}

// ---------------- mega kernel: fill | prep_w x2 | embed_ln ----------------
__global__ __launch_bounds__(256) void mega_kernel(
    const int* __restrict__ src, const int* __restrict__ dst,
    int* __restrict__ cursor, int* __restrict__ csr_src,
    const float* __restrict__ w0l, const float* __restrict__ w0r, ushort* __restrict__ wp0,
    const float* __restrict__ w1l, const float* __restrict__ w1r, ushort* __restrict__ wp1,
    const int* __restrict__ x_idx, const float* __restrict__ emb,
    const float* __restrict__ ln0g, const float* __restrict__ ln0b,
    float* __restrict__ x) {
  int bid = blockIdx.x;
  int t = threadIdx.x;
  if (bid < FILL_NB) {
    fill_body(bid, t, src, dst, cursor, csr_src);
  } else if (bid < FILL_NB + PREP_NB) {
    prep_body((bid - FILL_NB) * 256 + t, w0l, w0r, wp0);
  } else if (bid < FILL_NB + 2 * PREP_NB) {
    prep_body((bid - FILL_NB - PREP_NB) * 256 + t, w1l, w1r, wp1);
  } else {
    embed_body(bid - FILL_NB - 2 * PREP_NB, t, x_idx, emb, ln0g, ln0b, x);
  }
}

// ---------------- gather mean -> fragment-layout agg (edge loop unroll-2) ------
// af layout (ushort): [g16][jb(4)][lane(64)][hl(2)][e(8)], lane=(lq*16+l15),
// node n = g16*16+l15, k = jb*32 + lq*4 + (e&3) + 16*(e>>2).
__global__ __launch_bounds__(256) void gather_mean_kernel(
    const int* __restrict__ row_off, const int* __restrict__ csr_src,
    const float* __restrict__ x, ushort* __restrict__ af) {
  int t = threadIdx.x;
  int q = t & 31;
  int node = blockIdx.x * 8 + (t >> 5);
  if (node >= NN) return;
  int beg = row_off[node], end = row_off[node + 1];
  float4 acc = make_float4(0.f, 0.f, 0.f, 0.f);
  int e = beg;
  for (; e + 1 < end; e += 2) {
    int s0 = csr_src[e];
    int s1 = csr_src[e + 1];
    float4 v0 = ((const float4*)(x + (size_t)s0 * DIM))[q];
    float4 v1 = ((const float4*)(x + (size_t)s1 * DIM))[q];
    acc.x += v0.x; acc.y += v0.y; acc.z += v0.z; acc.w += v0.w;
    acc.x += v1.x; acc.y += v1.y; acc.z += v1.z; acc.w += v1.w;
  }
  if (e < end) {
    int s = csr_src[e];
    float4 v = ((const float4*)(x + (size_t)s * DIM))[q];
    acc.x += v.x; acc.y += v.y; acc.z += v.z; acc.w += v.w;
  }
  float sc = 1.0f / fmaxf((float)(end - beg), 1.0f);
  acc.x *= sc; acc.y *= sc; acc.z *= sc; acc.w *= sc;
  ushort4 hi, lo;
  hi.x = f2bf(acc.x); lo.x = f2bf(acc.x - bf2f(hi.x));
  hi.y = f2bf(acc.y); lo.y = f2bf(acc.y - bf2f(hi.y));
  hi.z = f2bf(acc.z); lo.z = f2bf(acc.z - bf2f(hi.z));
  hi.w = f2bf(acc.w); lo.w = f2bf(acc.w - bf2f(hi.w));
  int g = node >> 4, l15n = node & 15;
  int jb = q >> 3, lqw = q & 3, ebase = q & 4;
  size_t base = (((size_t)g * 4 + jb) * 64 + lqw * 16 + l15n) * 16;
  *(ushort4*)(af + base + ebase) = hi;
  *(ushort4*)(af + base + 8 + ebase) = lo;
}

// ---------------- SAGE conv, TILE=64 (block-overlap test) ----------------
// out = relu([agg|x] @ Wcat^T + bl) (+ optional fused LN), fp32 out.
// Block = 64 nodes, 4 waves, each wave 16 nodes x 128 h. LDS 16 KB.
// Phases 0,1: x self-half staged. Phases 2,3: agg from af frags.
// B fragments direct from pre-permuted wp (L2-resident). No min-wave bound
// (r12 lesson: forcing occupancy past the VGPR cliff spills).
__global__ __launch_bounds__(256) void conv_mfma_kernel(
    const float* __restrict__ xln, const ushort* __restrict__ af,
    const ushort* __restrict__ wp, const float* __restrict__ bl,
    const float* __restrict__ lng, const float* __restrict__ lnb,
    float* __restrict__ out, int do_ln) {
  __shared__ ushort Xs[2][64 * 64];  // 16 KB: [hi/lo][row*64 + permuted k]
  const int t = threadIdx.x;
  const int lane = t & 63;
  const int wv = t >> 6;
  const int l15 = lane & 15;
  const int lq = lane >> 4;
  const int nbase = blockIdx.x * 64;

  f32x4 acc[8];
#pragma unroll
  for (int b = 0; b < 8; ++b) acc[b] = (f32x4){0.f, 0.f, 0.f, 0.f};

  const int srow = t >> 2;   // staging row 0..63
  const int sq4 = t & 3;     // quad group
  const int gn_s = nbase + srow;
  const bool sval = gn_s < NN;
  char* lds_hi = (char*)&Xs[0][0];
  char* lds_lo = (char*)&Xs[1][0];
  const int sswz = (srow & 7) << 4;

  // ======== phases 0,1: x self-half (staged), W slice pk = ph+2 ========
#pragma unroll 1
  for (int ph = 0; ph < 2; ++ph) {
    if (ph) __syncthreads();
    const int kb = ph * 64;
#pragma unroll
    for (int i = 0; i < 4; ++i) {
      int qd = i * 4 + sq4;
      float4 v = make_float4(0.f, 0.f, 0.f, 0.f);
      if (sval) v = *(const float4*)(xln + (size_t)gn_s * DIM + kb + qd * 4);
      int j = qd >> 3;
      int a = qd & 7;
      int inner = j * 64 + ((a < 4) ? a * 16 : (a - 4) * 16 + 8);
      int off = srow * 128 + inner;
      ushort4 hi, lo;
      hi.x = f2bf(v.x); lo.x = f2bf(v.x - bf2f(hi.x));
      hi.y = f2bf(v.y); lo.y = f2bf(v.y - bf2f(hi.y));
      hi.z = f2bf(v.z); lo.z = f2bf(v.z - bf2f(hi.z));
      hi.w = f2bf(v.w); lo.w = f2bf(v.w - bf2f(hi.w));
      *(ushort4*)(lds_hi + (off ^ sswz)) = hi;
      *(ushort4*)(lds_lo + (off ^ sswz)) = lo;
    }
    __syncthreads();
    const int pk = ph + 2;  // wr half of Wcat
#pragma unroll
    for (int j = 0; j < 2; ++j) {
      int row = wv * 16 + l15;
      int off = row * 128 + j * 64 + lq * 16;
      int sw = (row & 7) << 4;
      short8_t ahi = *(short8_t*)(lds_hi + (off ^ sw));
      short8_t alo = *(short8_t*)(lds_lo + (off ^ sw));
#pragma unroll
      for (int ht = 0; ht < 8; ++ht) {
        short8_t bhi = *(const short8_t*)(wp + (((pk * 2 + 0) * 2 + j) * 8 + ht) * 512 + lane * 8);
        short8_t blo = *(const short8_t*)(wp + (((pk * 2 + 1) * 2 + j) * 8 + ht) * 512 + lane * 8);
        acc[ht] = __builtin_amdgcn_mfma_f32_16x16x32_bf16(ahi, bhi, acc[ht], 0, 0, 0);
        acc[ht] = __builtin_amdgcn_mfma_f32_16x16x32_bf16(alo, bhi, acc[ht], 0, 0, 0);
        acc[ht] = __builtin_amdgcn_mfma_f32_16x16x32_bf16(ahi, blo, acc[ht], 0, 0, 0);
      }
    }
  }

  // ======== phases 2,3: agg half direct from fragments, W slice pk = ph-2 ====
  const int g = blockIdx.x * 4 + wv;
#pragma unroll 1
  for (int ph = 2; ph < 4; ++ph) {
    const int pk = ph - 2;  // wl half of Wcat
#pragma unroll
    for (int j = 0; j < 2; ++j) {
      int jb = (ph & 1) * 2 + j;
      short8_t ahi, alo;
      if (g < NGRP) {
        size_t base = (((size_t)g * 4 + jb) * 64 + lane) * 16;
        ahi = *(const short8_t*)(af + base);
        alo = *(const short8_t*)(af + base + 8);
      } else {
        ahi = (short8_t){0, 0, 0, 0, 0, 0, 0, 0};
        alo = (short8_t){0, 0, 0, 0, 0, 0, 0, 0};
      }
#pragma unroll
      for (int ht = 0; ht < 8; ++ht) {
        short8_t bhi = *(const short8_t*)(wp + (((pk * 2 + 0) * 2 + j) * 8 + ht) * 512 + lane * 8);
        short8_t blo = *(const short8_t*)(wp + (((pk * 2 + 1) * 2 + j) * 8 + ht) * 512 + lane * 8);
        acc[ht] = __builtin_amdgcn_mfma_f32_16x16x32_bf16(ahi, bhi, acc[ht], 0, 0, 0);
        acc[ht] = __builtin_amdgcn_mfma_f32_16x16x32_bf16(alo, bhi, acc[ht], 0, 0, 0);
        acc[ht] = __builtin_amdgcn_mfma_f32_16x16x32_bf16(ahi, blo, acc[ht], 0, 0, 0);
      }
    }
  }

  // ======== epilogue: bias + relu (+ fused LN), fp32 row-major store ========
#pragma unroll
  for (int ht = 0; ht < 8; ++ht) {
    float bv = bl[ht * 16 + l15];
#pragma unroll
    for (int r = 0; r < 4; ++r) acc[ht][r] = fmaxf(acc[ht][r] + bv, 0.f);
  }
  if (do_ln) {
    float gg[8], bb[8];
#pragma unroll
    for (int ht = 0; ht < 8; ++ht) {
      gg[ht] = lng[ht * 16 + l15];
      bb[ht] = lnb[ht * 16 + l15];
    }
#pragma unroll
    for (int r = 0; r < 4; ++r) {
      float s = 0.f, sq = 0.f;
#pragma unroll
      for (int ht = 0; ht < 8; ++ht) {
        float v = acc[ht][r];
        s += v;
        sq += v * v;
      }
#pragma unroll
      for (int msk = 1; msk < 16; msk <<= 1) {
        s += __shfl_xor(s, msk);
        sq += __shfl_xor(sq, msk);
      }
      float m = s * (1.0f / 128.0f);
      float var = sq * (1.0f / 128.0f) - m * m;
      float rstd = rsqrtf(var + 1e-5f);
      int node = nbase + wv * 16 + lq * 4 + r;
      if (node < NN) {
#pragma unroll
        for (int ht = 0; ht < 8; ++ht)
          out[(size_t)node * DIM + ht * 16 + l15] =
              (acc[ht][r] - m) * rstd * gg[ht] + bb[ht];
      }
    }
  } else {
#pragma unroll
    for (int r = 0; r < 4; ++r) {
      int node = nbase + wv * 16 + lq * 4 + r;
      if (node < NN) {
#pragma unroll
        for (int ht = 0; ht < 8; ++ht)
          out[(size_t)node * DIM + ht * 16 + l15] = acc[ht][r];
      }
    }
  }
}

// ---------------- mean pool over sorted batch ----------------
#define PCHUNK 128
__global__ __launch_bounds__(128) void pool_kernel(const float* __restrict__ x,
                                                   const int* __restrict__ batch,
                                                   float* __restrict__ pool,
                                                   float* __restrict__ cnt) {
  int f = threadIdx.x;
  int n0 = blockIdx.x * PCHUNK;
  float acc = 0.f;
  int cur = batch[n0];
  int runlen = 0;
  for (int i = 0; i < PCHUNK; ++i) {
    int n = n0 + i;
    if (n >= NN) break;
    int bg = batch[n];
    if (bg != cur) {
      atomicAdd(&pool[cur * DIM + f], acc);
      if (f == 0) atomicAdd(&cnt[cur], (float)runlen);
      acc = 0.f;
      runlen = 0;
      cur = bg;
    }
    acc += x[(size_t)n * DIM + f];
    runlen++;
  }
  if (runlen > 0) {
    atomicAdd(&pool[cur * DIM + f], acc);
    if (f == 0) atomicAdd(&cnt[cur], (float)runlen);
  }
}

// ---------------- MLP head ----------------
__global__ __launch_bounds__(128) void head_kernel(
    const float* __restrict__ pool, const float* __restrict__ cnt,
    const float* __restrict__ w1, const float* __restrict__ b1,
    const float* __restrict__ w2, const float* __restrict__ b2,
    float* __restrict__ out) {
  __shared__ float gsh[128];
  __shared__ float h[64];
  int g = blockIdx.x;
  int t = threadIdx.x;
  float ic = 1.0f / fmaxf(cnt[g], 1.0f);
  gsh[t] = pool[g * DIM + t] * ic;
  __syncthreads();
  if (t < 64) {
    float a = b1[t];
#pragma unroll 8
    for (int k = 0; k < 128; ++k) a += gsh[k] * w1[t * 128 + k];
    h[t] = fmaxf(a, 0.f);
  }
  __syncthreads();
  if (t < 2) {
    float a = b2[t];
#pragma unroll
    for (int k = 0; k < 64; ++k) a += h[k] * w2[t * 64 + k];
    out[g * 2 + t] = a;
  }
}

extern "C" void kernel_launch(void* const* d_in, const int* in_sizes, int n_in,
                              void* d_out, int out_size, void* d_ws, size_t ws_size,
                              hipStream_t stream) {
  const int* x_idx = (const int*)d_in[0];
  const int* eidx = (const int*)d_in[1];
  const int* batch = (const int*)d_in[2];
  const float* emb = (const float*)d_in[3];
  const float* ln0g = (const float*)d_in[4];
  const float* ln0b = (const float*)d_in[5];
  const float* w0l = (const float*)d_in[6];
  const float* b0l = (const float*)d_in[7];
  const float* w0r = (const float*)d_in[8];
  const float* ln1g = (const float*)d_in[9];
  const float* ln1b = (const float*)d_in[10];
  const float* w1l = (const float*)d_in[11];
  const float* b1l = (const float*)d_in[12];
  const float* w1r = (const float*)d_in[13];
  const float* mw1 = (const float*)d_in[14];
  const float* mb1 = (const float*)d_in[15];
  const float* mw2 = (const float*)d_in[16];
  const float* mb2 = (const float*)d_in[17];
  float* out = (float*)d_out;

  float* ws = (float*)d_ws;
  float* x = ws;                                   // NN*DIM fp32
  ushort* af = (ushort*)(x + (size_t)NN * DIM);    // NN*DIM*2 ushort (frag agg)
  float* pool = (float*)(af + (size_t)NN * DIM * 2);  // NG*DIM
  float* cnt = pool + (size_t)NG * DIM;            // NG
  int* degi = (int*)(cnt + NG);                    // NN (contig for one memset)
  int* excl = degi + NN;                           // NN
  int* row_off = excl + NN;                        // NN+1
  int* cursor = row_off + NN + 1;                  // NN
  int* bsum = cursor + NN;                         // 512
  int* csr_src = bsum + 512;                       // NE
  ushort* wp0 = (ushort*)(csr_src + NE);           // 65536 ushort each
  ushort* wp1 = wp0 + 65536;

  const int* src = eidx;
  const int* dst = eidx + NE;

  // one memset: pool + cnt + degi are contiguous
  hipMemsetAsync(pool, 0, ((size_t)NG * DIM + NG + NN) * sizeof(float), stream);

  deg_int_kernel<<<FILL_NB, 256, 0, stream>>>(dst, degi);
  scan1_kernel<<<NB_SCAN, 256, 0, stream>>>(degi, excl, bsum);
  scan23_kernel<<<NB_SCAN, 256, 0, stream>>>(excl, bsum, row_off, cursor);
  mega_kernel<<<FILL_NB + 2 * PREP_NB + EMB_NB, 256, 0, stream>>>(
      src, dst, cursor, csr_src, w0l, w0r, wp0, w1l, w1r, wp1, x_idx, emb, ln0g, ln0b, x);

  // layer 0 (conv epilogue applies LN1, in-place x)
  gather_mean_kernel<<<(NN + 7) / 8, 256, 0, stream>>>(row_off, csr_src, x, af);
  conv_mfma_kernel<<<(NN + 63) / 64, 256, 0, stream>>>(x, af, wp0, b0l, ln1g, ln1b, x, 1);
  // layer 1 (plain relu epilogue, in-place x)
  gather_mean_kernel<<<(NN + 7) / 8, 256, 0, stream>>>(row_off, csr_src, x, af);
  conv_mfma_kernel<<<(NN + 63) / 64, 256, 0, stream>>>(x, af, wp1, b1l, (const float*)0, (const float*)0, x, 0);

  pool_kernel<<<(NN + PCHUNK - 1) / PCHUNK, 128, 0, stream>>>(x, batch, pool, cnt);
  head_kernel<<<NG, 128, 0, stream>>>(pool, cnt, mw1, mb1, mw2, mb2, out);
}